// Round 5
// baseline (148.017 us; speedup 1.0000x reference)
//
#include <hip/hip_runtime.h>
#include <math.h>

#define A_ 5
#define C_ 20
#define N_ 64
#define H_ 52
#define W_ 52
#define HW_ (H_ * W_)        // 2704
#define M_ 32
#define CH_ (A_ * (5 + C_))  // 125
#define CPB 64               // cells per block
#define NBX ((HW_ + CPB - 1) / CPB)  // 43
#define NBLK (NBX * N_)              // 2752

// Block = 320 threads = 5 waves; wave a = anchor a for 64 cells.
// Slim IoU loop: direct iou via v_rcp_f32 (1 cmp + 1 max + 1 cndmask per iter
// instead of cross-mult + 3 cndmasks). rcp err 2^-22 only affects exact ties.
__global__ __launch_bounds__(320) void yolo_main(
    const float* __restrict__ x,       // (N, 125, H, W)
    const float* __restrict__ anchors, // (5, 2)
    const float* __restrict__ gt,      // (N, 32, 4)
    const int* __restrict__ glab,      // (N, 32)
    const void* img_h_p, const void* img_w_p,
    float* __restrict__ ws)            // (NBLK, 3)
{
    // SoA planes: 0=iou 1=bm 2=ov 3=x1 4=y1 5=x2 6=y2  (8.75 KB)
    __shared__ float s_c[7][A_][CPB];

    const int tid  = threadIdx.x;
    const int a    = tid >> 6;
    const int lane = tid & 63;
    const int n    = blockIdx.y;
    const int cell = blockIdx.x * CPB + lane;
    const bool valid = cell < HW_;

    int ibw = *(const int*)img_w_p;
    float img_w = (ibw > 0 && ibw < 1000000) ? (float)ibw : *(const float*)img_w_p;
    int ibh = *(const int*)img_h_p;
    float img_h = (ibh > 0 && ibh < 1000000) ? (float)ibh : *(const float*)img_h_p;
    const float sx = img_w / (float)W_;
    const float sy = img_h / (float)H_;

    const float ax = anchors[2 * a];       // wave-uniform
    const float ay = anchors[2 * a + 1];

    float x1 = 0.f, y1 = 0.f, x2 = 0.f, y2 = 0.f, ov = 0.f, ap = 0.f;

    if (valid) {
        const int wi = cell % W_;
        const int hi = cell / W_;
        const size_t base = (size_t)n * CH_ * HW_ + (size_t)a * 25 * HW_ + cell;
        float t0 = x[base];
        float t1 = x[base + (size_t)HW_];
        float t2 = x[base + 2 * (size_t)HW_];
        float t3 = x[base + 3 * (size_t)HW_];
        float t4 = x[base + 4 * (size_t)HW_];

        float bx = 1.f / (1.f + __expf(-t0)) + (float)wi * sx;
        float by = 1.f / (1.f + __expf(-t1)) + (float)hi * sy;
        float bw = sx * ax * __expf(t2);
        float bh = sy * ay * __expf(t3);
        x1 = bx; y1 = by; x2 = bx + bw; y2 = by + bh;
        ov = 1.f / (1.f + __expf(-t4));
        ap = (x2 - x1) * (y2 - y1);   // corner-difference form, matches reference
    }

    // IoU argmax over 32 GT boxes (strict >, first-max; init 0 matches
    // jnp.argmax-of-zeros = 0)
    float biou = 0.f;
    int   bm = 0;
    const float4* gtv = (const float4*)(gt + (size_t)n * M_ * 4);
    #pragma unroll 8
    for (int m = 0; m < M_; ++m) {
        float4 g = gtv[m];                    // uniform address -> scalar load
        float apm = ap + (g.z - g.x) * (g.w - g.y);
        float wxi = fmaxf(fminf(x2, g.z) - fmaxf(x1, g.x), 0.f);
        float hyi = fmaxf(fminf(y2, g.w) - fmaxf(y1, g.y), 0.f);
        float inter = wxi * hyi;
        // union > 0 always (both areas positive); iou finite, >= 0
        float iou = inter * __builtin_amdgcn_rcpf(apm - inter);
        if (iou > biou) { biou = iou; bm = m; }
    }

    s_c[0][a][lane] = biou;
    s_c[1][a][lane] = __int_as_float(bm);
    s_c[2][a][lane] = ov;
    s_c[3][a][lane] = x1;
    s_c[4][a][lane] = y1;
    s_c[5][a][lane] = x2;
    s_c[6][a][lane] = y2;
    __syncthreads();

    // ---- tail: wave 0 selects best anchor per cell, computes losses ----
    if (tid < 64) {
        float obj = 0.f, bbx = 0.f, clf = 0.f;

        float Bi = 0.f, O = 0.f;
        float X1 = 0.f, Y1 = 0.f, X2 = 0.f, Y2 = 0.f;
        int Ba = 0, Bm = 0;
        float bomax = -1e30f;
        #pragma unroll
        for (int aa = 0; aa < A_; ++aa) {
            float ci = s_c[0][aa][lane];
            float co = s_c[2][aa][lane];
            bomax = fmaxf(bomax, co);
            bool upd = (aa == 0) || (ci > Bi);   // strict > = first-max ties
            if (upd) {
                Bi = ci; Ba = aa; O = co;
                Bm = __float_as_int(s_c[1][aa][lane]);
                X1 = s_c[3][aa][lane]; Y1 = s_c[4][aa][lane];
                X2 = s_c[5][aa][lane]; Y2 = s_c[6][aa][lane];
            }
        }

        if (valid) {
            if (Bi > 0.f) {
                float d = O - Bi;                 // Bi == max iou
                obj = d * d;

                float4 g = ((const float4*)gt)[n * M_ + Bm];
                float d0 = X1 - g.x;
                float d1 = Y1 - g.y;
                float d2 = sqrtf(X2) - sqrtf(g.z);
                float d3 = sqrtf(Y2) - sqrtf(g.w);
                bbx = d0 * d0 + d1 * d1 + d2 * d2 + d3 * d3;

                // CE: 20 score loads issued up-front (full unroll), online softmax
                const size_t sb = (size_t)n * CH_ * HW_ + (size_t)(Ba * 25 + 5) * HW_ + cell;
                const int lab = glab[n * M_ + Bm];
                float mx = -1e30f, se = 0.f, scl = 0.f;
                #pragma unroll
                for (int j = 0; j < C_; ++j) {
                    float v = x[sb + (size_t)j * HW_];
                    float nm = fmaxf(mx, v);
                    se = se * __expf(mx - nm) + __expf(v - nm);
                    mx = nm;
                    scl = (j == lab) ? v : scl;
                }
                clf = mx + __logf(se) - scl;
            } else {
                obj = 0.5f * bomax * bomax;
            }
        }

        #pragma unroll
        for (int off = 32; off > 0; off >>= 1) {
            obj += __shfl_down(obj, off, 64);
            bbx += __shfl_down(bbx, off, 64);
            clf += __shfl_down(clf, off, 64);
        }
        if (tid == 0) {
            const int bid = blockIdx.y * gridDim.x + blockIdx.x;
            ws[bid * 3 + 0] = obj;
            ws[bid * 3 + 1] = bbx;
            ws[bid * 3 + 2] = clf;
        }
    }
}

__global__ __launch_bounds__(256) void yolo_reduce(
    const float* __restrict__ ws, float* __restrict__ out)
{
    __shared__ float s_red[4][3];
    const int tid = threadIdx.x;
    float o = 0.f, b = 0.f, c = 0.f;
    for (int e = tid; e < NBLK; e += 256) {
        o += ws[e * 3 + 0];
        b += ws[e * 3 + 1];
        c += ws[e * 3 + 2];
    }
    #pragma unroll
    for (int off = 32; off > 0; off >>= 1) {
        o += __shfl_down(o, off, 64);
        b += __shfl_down(b, off, 64);
        c += __shfl_down(c, off, 64);
    }
    const int wid = tid >> 6;
    if ((tid & 63) == 0) {
        s_red[wid][0] = o; s_red[wid][1] = b; s_red[wid][2] = c;
    }
    __syncthreads();
    if (tid == 0) {
        float oo = 0.f, bb = 0.f, cc = 0.f;
        #pragma unroll
        for (int w = 0; w < 4; ++w) {
            oo += s_red[w][0]; bb += s_red[w][1]; cc += s_red[w][2];
        }
        out[0] = oo; out[1] = bb; out[2] = cc;
    }
}

extern "C" void kernel_launch(void* const* d_in, const int* in_sizes, int n_in,
                              void* d_out, int out_size, void* d_ws, size_t ws_size,
                              hipStream_t stream) {
    const float* x    = (const float*)d_in[0];
    const float* anch = (const float*)d_in[1];
    const float* gt   = (const float*)d_in[2];
    const int*   gl   = (const int*)d_in[3];
    const void*  ih   = d_in[4];
    const void*  iw   = d_in[5];
    float* out = (float*)d_out;
    float* ws  = (float*)d_ws;

    dim3 grid(NBX, N_);
    yolo_main<<<grid, dim3(320), 0, stream>>>(x, anch, gt, gl, ih, iw, ws);
    yolo_reduce<<<1, 256, 0, stream>>>(ws, out);
}